// Round 3
// baseline (169.503 us; speedup 1.0000x reference)
//
#include <hip/hip_runtime.h>

constexpr int kB    = 16;
constexpr int kM    = 512;
constexpr int kS    = 32;
constexpr int kE    = 128;
constexpr int kV    = 32000;
constexpr int kVN   = kV - 1;   // nil (zero) row index
constexpr int kMS   = 132;      // padded LDS stride for hops mem tile
constexpr int kQ    = 16;       // blocks per batch element (R13: was 4)
constexpr int kRows = kM / kQ;  // 32 memory rows per block

// -------------------------------------------------------------------------
// Kernel 1: story embeddings (R6-proven, untouched). 2 rows per 256-thread
// block, grid = 4096. Streams 268 MB of 512B random-gather traffic at the
// memory-system rate (~6.6 TB/s) -> ~40.5 µs structural floor.
// enc[s][e] = 1 + (e-63)(s-15)/1024 (exact f32 match of numpy formula).
// Block 0 zeroes the kB+1 barrier counters for the hops kernel.
// -------------------------------------------------------------------------
__global__ __launch_bounds__(256) void embed_stories_kernel(
    const int*   __restrict__ stories,   // [B,M,S]
    const float* __restrict__ st_bias,   // [VN,E]
    const float* __restrict__ out_bias,  // [VN,E]
    const float* __restrict__ mem_bias,  // [M,E]
    float*       __restrict__ memory,    // [B,M,E]
    float*       __restrict__ output,    // [B,M,E]
    unsigned*    __restrict__ bar)       // [B+1] counters -> zeroed by block 0
{
    __shared__ int sidx[2][kS];
    __shared__ __align__(16) float pm[8][kE];
    __shared__ __align__(16) float po[8][kE];

    const int t    = threadIdx.x;
    const int row0 = blockIdx.x * 2;
    if (t < 64) sidx[t >> 5][t & 31] = stories[row0 * kS + t];
    if (blockIdx.x == 0 && t < kB + 1) bar[t] = 0u;
    __syncthreads();

    const int g    = t >> 5;
    const int lane = t & 31;
    const int p    = g >> 2;       // row of pair
    const int ph   = g & 3;        // s-phase
    const int e0   = lane * 4;
    const float ef0 = (float)(e0 - 63), ef1 = (float)(e0 - 62);
    const float ef2 = (float)(e0 - 61), ef3 = (float)(e0 - 60);

    float4 am = {0.f, 0.f, 0.f, 0.f};
    float4 ao = {0.f, 0.f, 0.f, 0.f};
    #pragma unroll
    for (int j = 0; j < 8; ++j) {
        const int s   = ph * 8 + j;
        const int idx = sidx[p][s];
        const int ci  = idx < kVN ? idx : (kVN - 1);       // clamped row
        const float live = (idx < kVN) ? 1.0f : 0.0f;      // nil -> weight 0
        const float sf = (float)(s - 15) * (1.0f / 1024.0f);
        const float4 vm = *(const float4*)(st_bias  + (size_t)ci * kE + e0);
        const float4 vo = *(const float4*)(out_bias + (size_t)ci * kE + e0);
        const float c0 = fmaf(ef0, sf, 1.0f) * live;
        const float c1 = fmaf(ef1, sf, 1.0f) * live;
        const float c2 = fmaf(ef2, sf, 1.0f) * live;
        const float c3 = fmaf(ef3, sf, 1.0f) * live;
        am.x = fmaf(vm.x, c0, am.x); am.y = fmaf(vm.y, c1, am.y);
        am.z = fmaf(vm.z, c2, am.z); am.w = fmaf(vm.w, c3, am.w);
        ao.x = fmaf(vo.x, c0, ao.x); ao.y = fmaf(vo.y, c1, ao.y);
        ao.z = fmaf(vo.z, c2, ao.z); ao.w = fmaf(vo.w, c3, ao.w);
    }
    *(float4*)&pm[g][e0] = am;
    *(float4*)&po[g][e0] = ao;
    __syncthreads();

    const int pr = t >> 7;
    const int e  = t & 127;
    const int row = row0 + pr;
    const int m   = row & (kM - 1);
    const float sm = pm[pr * 4 + 0][e] + pm[pr * 4 + 1][e] +
                     pm[pr * 4 + 2][e] + pm[pr * 4 + 3][e];
    const float so = po[pr * 4 + 0][e] + po[pr * 4 + 1][e] +
                     po[pr * 4 + 2][e] + po[pr * 4 + 3][e];
    memory[(size_t)row * kE + e] = sm + mem_bias[m * kE + e];
    output[(size_t)row * kE + e] = so;
}

// -------------------------------------------------------------------------
// Fence-free spin barrier (R4/R6-proven). Cross-block data via agent-scope
// RELAXED atomics (performed at the device coherence point — no
// cache-maintenance storms, R3 lesson).
// -------------------------------------------------------------------------
__device__ __forceinline__ void group_barrier(unsigned* ctr, unsigned target)
{
    __syncthreads();
    if (threadIdx.x == 0) {
        __hip_atomic_fetch_add(ctr, 1u, __ATOMIC_RELEASE, __HIP_MEMORY_SCOPE_AGENT);
        while (__hip_atomic_load(ctr, __ATOMIC_RELAXED, __HIP_MEMORY_SCOPE_AGENT) < target)
            __builtin_amdgcn_s_sleep(2);
    }
    __syncthreads();
}
__device__ __forceinline__ void cstore(float* p, float v) {
    __hip_atomic_store(p, v, __ATOMIC_RELAXED, __HIP_MEMORY_SCOPE_AGENT);
}
__device__ __forceinline__ float cload(const float* p) {
    return __hip_atomic_load(p, __ATOMIC_RELAXED, __HIP_MEMORY_SCOPE_AGENT);
}

// -------------------------------------------------------------------------
// Kernel 2 (REGULAR launch, 256 blocks x 1024 threads): q-embed + 3 hops +
// fused final matmul. R13: full-device version of the R12 kernel (was 64
// blocks = 25% of CUs; every phase was latency/BW-starved at Occ ~10%,
// VALUBusy 1.9%). Now 16 blocks per b (32 memory rows each, bids ≡ b mod
// 16 -> same XCD under round-robin), tail = 125 wf columns per block
// (16.4 MB over 256 CUs ≈ 2.6 µs vs ~10 µs on 64).
// -------------------------------------------------------------------------
__global__ __launch_bounds__(1024) void hops_final_kernel(
    const int*   __restrict__ queries,   // [B,S]
    const float* __restrict__ q_bias,    // [VN,E]
    const float* __restrict__ memory,    // [B,M,E]
    const float* __restrict__ output,    // [B,M,E]
    const float* __restrict__ w_int,     // [E,E]
    const float* __restrict__ w_out,     // [E,E]
    const float* __restrict__ wf,        // [E,V]
    float*       __restrict__ numer,     // [2,B,kQ,E]
    float*       __restrict__ denom,     // [2,B,kQ]
    float*                    xg,        // [E,B] transposed relu_x exchange
    unsigned*    __restrict__ bar,       // [B+1] counters (zeroed by embed)
    float*       __restrict__ out)       // [B,V]
{
    // Pool carving: hops phase uses [rows|out] = 8320 floats; tail reuses
    // the pool as ps[7][128][17] (15232) + sx[2048] = 17280 floats (69 KB).
    constexpr int kPS  = 7 * 128 * 17;          // 15232
    constexpr int kPool = kPS + kE * kB;        // 17280
    __shared__ __align__(16) float pool[kPool];
    __shared__ __align__(16) float part8[8][kE];
    __shared__ float sc_q[kRows];
    __shared__ __align__(16) float q_s[kE];
    __shared__ float xb[kE];

    float* mem_lds = pool;                      // [kRows][kMS]
    float* out_lds = pool + kRows * kMS;        // [kRows][kE]

    const int bid = blockIdx.x;
    const int b   = bid & 15;      // XCD-colocated groups (bids ≡ b mod 16)
    const int qtr = bid >> 4;      // [0,16): which 32-row slice of M
    const int t   = threadIdx.x;
    unsigned* ctr = bar + b;

    // ---- stage this block's 32 mem/out rows: 1 float4/thread/array ----
    {
        const size_t base = ((size_t)b * kM + qtr * kRows) * kE;
        const int rr = t >> 5, ff = (t & 31) * 4;
        *(float4*)&mem_lds[rr * kMS + ff] =
            *(const float4*)&memory[base + (size_t)rr * kE + ff];
        *(float4*)&out_lds[rr * kE  + ff] =
            *(const float4*)&output[base + (size_t)rr * kE + ff];
    }

    // ---- q-embed: gathers issue concurrently with the staging above ----
    if (t < 256) {
        const int g = t >> 5, lane = t & 31, e0 = lane * 4;
        const float f0 = (float)(e0 - 63) * (1.0f / 1024.0f);
        const float f1 = (float)(e0 - 62) * (1.0f / 1024.0f);
        const float f2 = (float)(e0 - 61) * (1.0f / 1024.0f);
        const float f3 = (float)(e0 - 60) * (1.0f / 1024.0f);
        float4 a = {0.f, 0.f, 0.f, 0.f};
        #pragma unroll
        for (int j = 0; j < 4; ++j) {
            const int s   = g * 4 + j;
            const int idx = queries[b * kS + s];          // L1-hot, 2 KB table
            const int ci  = idx < kVN ? idx : (kVN - 1);
            const float live = (idx < kVN) ? 1.0f : 0.0f;
            const float sf = (float)(s - 15);
            const float4 v = *(const float4*)&q_bias[(size_t)ci * kE + e0];
            a.x = fmaf(v.x, fmaf(f0, sf, 1.f) * live, a.x);
            a.y = fmaf(v.y, fmaf(f1, sf, 1.f) * live, a.y);
            a.z = fmaf(v.z, fmaf(f2, sf, 1.f) * live, a.z);
            a.w = fmaf(v.w, fmaf(f3, sf, 1.f) * live, a.w);
        }
        *(float4*)&part8[g][e0] = a;
    }
    __syncthreads();
    if (t < kE) {
        float s = 0.f;
        #pragma unroll
        for (int g = 0; g < 8; ++g) s += part8[g][t];
        q_s[t] = s;
    }
    __syncthreads();

    for (int hop = 0; hop < 3; ++hop) {
        // ---- scores for own 32 rows: 32 lanes x 4 e per row ----
        {
            const int rw = t >> 5, sub = t & 31;
            const float4 q4 = ((const float4*)q_s)[sub];
            const float4 m4 = *(const float4*)&mem_lds[rw * kMS + sub * 4];
            float d = 0.f;
            d = fmaf(m4.x, q4.x, d); d = fmaf(m4.y, q4.y, d);
            d = fmaf(m4.z, q4.z, d); d = fmaf(m4.w, q4.w, d);
            d += __shfl_down(d, 16, 32);
            d += __shfl_down(d, 8, 32);
            d += __shfl_down(d, 4, 32);
            d += __shfl_down(d, 2, 32);
            d += __shfl_down(d, 1, 32);
            if (sub == 0) sc_q[rw] = __expf(d);   // no max-sub: |s| = O(1)
        }
        __syncthreads();

        // ---- numer partial: 8 groups x 4 rows ----
        {
            const int grp = t >> 7, e = t & 127;
            float acc = 0.f;
            #pragma unroll
            for (int j = 0; j < 4; ++j)
                acc = fmaf(sc_q[grp * 4 + j], out_lds[(grp * 4 + j) * kE + e], acc);
            part8[grp][e] = acc;
        }
        __syncthreads();

        const int pb = hop & 1;
        float* nq = numer + (((size_t)pb * kB + b) * kQ + qtr) * kE;
        if (t < kE) {
            float s = 0.f;
            #pragma unroll
            for (int g = 0; g < 8; ++g) s += part8[g][t];
            cstore(&nq[t], s);
        } else if (t < 160) {
            const int l = t - 128;
            float s2 = sc_q[l];
            s2 += __shfl_down(s2, 16, 32);
            s2 += __shfl_down(s2, 8, 32);
            s2 += __shfl_down(s2, 4, 32);
            s2 += __shfl_down(s2, 2, 32);
            s2 += __shfl_down(s2, 1, 32);
            if (l == 0) cstore(&denom[((size_t)pb * kB + b) * kQ + qtr], s2);
        }

        group_barrier(ctr, (unsigned)kQ * (hop + 1));

        // ---- combine: xb = q + sum(numer)/sum(denom), 16-way ----
        if (t < kE) {
            const float* nn = numer + ((size_t)pb * kB + b) * kQ * kE;
            const float* dd = denom + ((size_t)pb * kB + b) * kQ;
            float ns = 0.f, ds = 0.f;
            #pragma unroll
            for (int j = 0; j < kQ; ++j) ns += cload(&nn[j * kE + t]);
            #pragma unroll
            for (int j = 0; j < kQ; ++j) ds += cload(&dd[j]);
            xb[t] = q_s[t] + ns / ds;
        }
        __syncthreads();

        // ---- q' = xb @ W (redundant, 8 k-groups of 16) ----
        {
            const int grp = t >> 7, e = t & 127;
            const float* w = (hop == 2) ? w_out : w_int;
            float acc = 0.f;
            #pragma unroll
            for (int j = 0; j < 16; ++j) {
                const int k = grp * 16 + j;
                acc = fmaf(xb[k], w[k * kE + e], acc);
            }
            part8[grp][e] = acc;
        }
        __syncthreads();
        if (t < kE) {
            float s = 0.f;
            #pragma unroll
            for (int g = 0; g < 8; ++g) s += part8[g][t];
            q_s[t] = s;
        }
        __syncthreads();
    }

    // ---- exchange relu_x: cstore -> device coherence point; all-256
    //      barrier; consumer caches never touched xg lines -> loads fill
    //      fresh (R12-proven pattern). ----
    if (qtr == 0 && t < kE) cstore(&xg[t * kB + b], fmaxf(q_s[t], 0.f));
    group_barrier(bar + kB, 256u);

    // ---- stage xg into LDS sx[e*16+b]; pool reused (hops tiles dead) ----
    float* ps = pool;               // [7][128][17] partials for h=1..7
    float* sx = pool + kPS;         // [2048]
    if (t < 512) {
        *(float4*)&sx[t * 4] = *(const float4*)&xg[t * 4];
    }
    __syncthreads();

    // ---- fused final: out[b, v] = relu_x[b,:] . wf[:, v] ----
    // 125 v-columns per block (256 x 125 = 32000 exactly); 8 e-groups of
    // 16; partials combined via padded LDS [7][128][17] (stride 17 -> max
    // 2-way bank aliasing = free). Only global loads in the loop are the
    // coalesced wf stream; xg reads are LDS broadcasts.
    {
        const int vt = t & 127;
        const int h  = t >> 7;
        const int v  = bid * 125 + vt;
        float acc[kB];
        #pragma unroll
        for (int b2 = 0; b2 < kB; ++b2) acc[b2] = 0.f;

        if (vt < 125) {
            const int e0 = h * 16;
            #pragma unroll
            for (int ei = 0; ei < 16; ++ei) {
                const int e = e0 + ei;
                const float wv = wf[(size_t)e * kV + v];
                const float* xr = &sx[e * kB];  // uniform addr -> broadcast
                #pragma unroll
                for (int b2 = 0; b2 < kB; ++b2)
                    acc[b2] = fmaf(xr[b2], wv, acc[b2]);
            }
            if (h > 0) {
                #pragma unroll
                for (int b2 = 0; b2 < kB; ++b2)
                    ps[(h - 1) * (128 * 17) + vt * 17 + b2] = acc[b2];
            }
        }
        __syncthreads();
        if (h == 0 && vt < 125) {
            #pragma unroll
            for (int b2 = 0; b2 < kB; ++b2) {
                float s = acc[b2];
                #pragma unroll
                for (int j = 0; j < 7; ++j)
                    s += ps[j * (128 * 17) + vt * 17 + b2];
                out[(size_t)b2 * kV + v] = s;
            }
        }
    }
}

// -------------------------------------------------------------------------
extern "C" void kernel_launch(void* const* d_in, const int* in_sizes, int n_in,
                              void* d_out, int out_size, void* d_ws, size_t ws_size,
                              hipStream_t stream)
{
    const int*   queries  = (const int*)  d_in[0];
    const int*   stories  = (const int*)  d_in[1];
    const float* q_bias   = (const float*)d_in[2];
    const float* st_bias  = (const float*)d_in[3];
    const float* mem_bias = (const float*)d_in[4];
    const float* out_bias = (const float*)d_in[5];
    const float* w_int    = (const float*)d_in[6];
    const float* w_out    = (const float*)d_in[7];
    const float* w_final  = (const float*)d_in[8];
    float* out = (float*)d_out;

    // ws layout (floats): memory | output | numer | denom | xg | bar
    float* memory = (float*)d_ws;
    float* output = memory + (size_t)kB * kM * kE;        // 1,048,576
    float* numer  = output + (size_t)kB * kM * kE;        // 1,048,576
    float* denom  = numer  + 2 * kB * kQ * kE;            // 65,536
    float* xg     = denom  + 2 * kB * kQ;                 // 512
    unsigned* bar = (unsigned*)(xg + kE * kB);            // 2,048

    embed_stories_kernel<<<dim3((kB * kM) / 2), dim3(256), 0, stream>>>(
        stories, st_bias, out_bias, mem_bias, memory, output, bar);

    hops_final_kernel<<<dim3(256), dim3(1024), 0, stream>>>(
        queries, q_bias, memory, output, w_int, w_out, w_final,
        numer, denom, xg, bar, out);
}